// Round 1
// baseline (123.631 us; speedup 1.0000x reference)
//
#include <hip/hip_runtime.h>
#include <cstdint>

typedef __bf16 bf16x8 __attribute__((ext_vector_type(8)));
typedef float floatx4 __attribute__((ext_vector_type(4)));

// M = 4096 rows, C(K) = 256. GEMM block tile 128x128, K-slab 64.
//
// Staged global layout (produced by transpose_stage, consumed by GEMM):
//   Xs[rb(32)][s(4)][kk(2)][rowhi(8)][quad(4)][rowlo(16)][8 bf16]
// holding element X[row = rb*128+rowhi*16+rowlo][k = s*64+kk*32+quad*8+j].
// Exactly the LDS image for conflict-free lane-linear ds_read_b128 fragment
// reads AND lane-linear global_load_lds staging.

#define OFF_X     (0u)
#define OFF_Y     (2u*1024*1024)
#define OFF_PMAX  (4u*1024*1024)
#define OFF_PSUM  (5u*1024*1024)
#define OFF_DIAG  (6u*1024*1024)
#define OFF_LPART (OFF_DIAG + 16384u)
#define OFF_CPART (OFF_LPART + 256u)
#define OFF_CNT   (OFF_CPART + 256u)   // 33 ints: cnt[0..31] per-bR, [32]=dcnt

#define AS1C(p) ((const __attribute__((address_space(1))) void*)(const void*)(p))
#define AS3(p)  ((__attribute__((address_space(3))) void*)(void*)(p))

// ---------------------------------------------------------------------------
// K0: pred/gt (B,N,C,H,W) fp32 -> staged bf16 layout. One block per slab
// (one (b,n) pair = 16 rows x 256 c, 16 KB contiguous input). Block 0 also
// zeroes the completion counters used by K1's fused epilogue (stream order +
// end-of-kernel agent-scope release makes them visible to K1's atomics).
// ---------------------------------------------------------------------------
__global__ __launch_bounds__(256) void transpose_stage(
    const float* __restrict__ pred, const float* __restrict__ gt,
    unsigned short* __restrict__ Xs, unsigned short* __restrict__ Ys,
    int* __restrict__ cnt) {
  int blk = blockIdx.x;
  const int t = threadIdx.x;
  if (blk == 0 && t < 33) cnt[t] = 0;
  const float* src;
  unsigned short* dst;
  int slab;
  if (blk < 256) { src = pred; dst = Xs; slab = blk; }
  else           { src = gt;   dst = Ys; slab = blk - 256; }
  const float* sb = src + slab * 4096;
  const int rb = slab >> 3, rowhi = slab & 7;
  #pragma unroll
  for (int half = 0; half < 2; ++half) {
    int c_ = half * 256 + t;                 // chunk id within slab, 0..511
    int rowlo = c_ & 15;
    int quad  = (c_ >> 4) & 3;
    int kk    = (c_ >> 6) & 1;
    int s     = c_ >> 7;
    int k0 = s * 64 + kk * 32 + quad * 8;
    unsigned int packed[4];
    #pragma unroll
    for (int jj = 0; jj < 4; ++jj) {
      unsigned int lohi[2];
      #pragma unroll
      for (int e = 0; e < 2; ++e) {
        float f = sb[(k0 + jj * 2 + e) * 16 + rowlo];
        unsigned int u = __float_as_uint(f);
        lohi[e] = (u + 0x7FFFu + ((u >> 16) & 1u)) >> 16;   // RNE -> bf16
      }
      packed[jj] = lohi[0] | (lohi[1] << 16);
    }
    unsigned short* o = dst + rb * 32768 +
        (unsigned)(s * 1024 + kk * 512 + rowhi * 64 + quad * 16 + rowlo) * 8;
    uint4 v; v.x = packed[0]; v.y = packed[1]; v.z = packed[2]; v.w = packed[3];
    *reinterpret_cast<uint4*>(o) = v;
  }
}

// ---------------------------------------------------------------------------
// K1: lossmat tile (128x128) = X @ Y^T, mfma_f32_16x16x32_bf16, 4 waves 2x2.
// Fused epilogue A: per-row (max, sum-exp) partials per 64-col group + diag.
// Fused epilogue B (last-block-per-bR): combine the 64 col-group partials for
// 128 rows -> per-bR (loss, correct) partial; last bR-finisher writes out.
// Per-row combine math is bitwise-identical to the old combine_rows kernel.
// ---------------------------------------------------------------------------
__global__ __launch_bounds__(256, 4) void gemm_softmax_combine(
    const unsigned short* __restrict__ Xs, const unsigned short* __restrict__ Ys,
    float* __restrict__ pmax, float* __restrict__ psum, float* __restrict__ diag,
    float* __restrict__ lpart, float* __restrict__ cpart,
    int* __restrict__ cnt, float* __restrict__ out) {
  __shared__ __align__(16) unsigned short As[8192];  // 16 KB: 128 rows x 64 k
  __shared__ __align__(16) unsigned short Bs[8192];
  __shared__ float ls[4], cs[4];
  __shared__ int lastflag;
  const int t = threadIdx.x;
  const int wave = t >> 6, lane = t & 63;
  const int rg = wave >> 1, cg = wave & 1;
  const int bR = blockIdx.x, bC = blockIdx.y;
  const unsigned short* Ag = Xs + bR * 32768;
  const unsigned short* Bg = Ys + bC * 32768;

  floatx4 acc[4][4];
  const floatx4 zero = {0.f, 0.f, 0.f, 0.f};
  #pragma unroll
  for (int i = 0; i < 4; ++i)
    #pragma unroll
    for (int j = 0; j < 4; ++j) acc[i][j] = zero;

  for (int s = 0; s < 4; ++s) {
    #pragma unroll
    for (int it = 0; it < 4; ++it) {
      int chunk = it * 256 + t;        // lane-linear: 16B per thread
      __builtin_amdgcn_global_load_lds(AS1C(Ag + s * 8192 + chunk * 8),
                                       AS3(As + chunk * 8), 16, 0, 0);
      __builtin_amdgcn_global_load_lds(AS1C(Bg + s * 8192 + chunk * 8),
                                       AS3(Bs + chunk * 8), 16, 0, 0);
    }
    __syncthreads();
    #pragma unroll
    for (int kk = 0; kk < 2; ++kk) {
      bf16x8 a[4], b[4];
      #pragma unroll
      for (int fr = 0; fr < 4; ++fr)
        a[fr] = *reinterpret_cast<const bf16x8*>(
            As + (unsigned)(kk * 512 + (rg * 4 + fr) * 64 + lane) * 8);
      #pragma unroll
      for (int fc = 0; fc < 4; ++fc)
        b[fc] = *reinterpret_cast<const bf16x8*>(
            Bs + (unsigned)(kk * 512 + (cg * 4 + fc) * 64 + lane) * 8);
      #pragma unroll
      for (int fr = 0; fr < 4; ++fr)
        #pragma unroll
        for (int fc = 0; fc < 4; ++fc)
          acc[fr][fc] = __builtin_amdgcn_mfma_f32_16x16x32_bf16(
              a[fr], b[fc], acc[fr][fc], 0, 0, 0);
    }
    if (s < 3) __syncthreads();
  }

  const int quad = lane >> 4, lc = lane & 15;

  // Diagonal extraction: row_local = fr*16+quad*4+reg, col_local = fc*16+lc.
  if (bR == bC && rg == cg) {
    #pragma unroll
    for (int fr = 0; fr < 4; ++fr)
      #pragma unroll
      for (int r = 0; r < 4; ++r)
        if (lc == quad * 4 + r)
          diag[bR * 128 + rg * 64 + fr * 16 + lc] = acc[fr][fr][r];
  }

  // Per-row partials over this wave's 64 cols.
  #pragma unroll
  for (int fr = 0; fr < 4; ++fr) {
    #pragma unroll
    for (int r = 0; r < 4; ++r) {
      float v0 = acc[fr][0][r], v1 = acc[fr][1][r];
      float v2 = acc[fr][2][r], v3 = acc[fr][3][r];
      float m = fmaxf(fmaxf(v0, v1), fmaxf(v2, v3));
      #pragma unroll
      for (int sh = 1; sh < 16; sh <<= 1) m = fmaxf(m, __shfl_xor(m, sh, 64));
      float ss = __expf(v0 - m) + __expf(v1 - m) +
                 __expf(v2 - m) + __expf(v3 - m);
      #pragma unroll
      for (int sh = 1; sh < 16; sh <<= 1) ss += __shfl_xor(ss, sh, 64);
      if (lc == 0) {
        int grow = bR * 128 + rg * 64 + fr * 16 + quad * 4 + r;
        int p = grow * 64 + bC * 2 + cg;
        pmax[p] = m; psum[p] = ss;
      }
    }
  }

  // ---- fused combine: release partials, last (bR,*) block combines. ----
  __syncthreads();                      // drains vmcnt: all stores issued
  if (t == 0) {
    __threadfence();                    // agent-scope release (L2 writeback)
    int old = atomicAdd(cnt + bR, 1);   // device-scope, LLC-serialized
    lastflag = (old == 31) ? 1 : 0;
  }
  __syncthreads();
  if (!lastflag) return;

  __threadfence();                      // acquire: invalidate stale L1/L2

  float lossr = 0.f, corr = 0.f;
  if (t < 128) {
    int row = bR * 128 + t;
    const float* pm = pmax + row * 64;
    const float* ps = psum + row * 64;
    float M = -3.4e38f;
    #pragma unroll 8
    for (int b = 0; b < 64; ++b) M = fmaxf(M, pm[b]);
    float S = 0.f;
    #pragma unroll 8
    for (int b = 0; b < 64; ++b) S += ps[b] * __expf(pm[b] - M);
    float d = diag[row];
    lossr = logf(S) + M - d;
    corr = (d == M) ? 1.f : 0.f;
  }
  #pragma unroll
  for (int sh = 1; sh < 64; sh <<= 1) {
    lossr += __shfl_xor(lossr, sh, 64);
    corr  += __shfl_xor(corr,  sh, 64);
  }
  if (lane == 0) { ls[wave] = lossr; cs[wave] = corr; }
  __syncthreads();
  if (t == 0) {
    lpart[bR] = ls[0] + ls[1] + ls[2] + ls[3];
    cpart[bR] = cs[0] + cs[1] + cs[2] + cs[3];
    __threadfence();                    // release per-bR partial
    int old2 = atomicAdd(cnt + 32, 1);  // dcnt
    if (old2 == 31) {
      __threadfence();                  // acquire all 32 partials
      float L = 0.f, C = 0.f;
      for (int i = 0; i < 32; ++i) { L += lpart[i]; C += cpart[i]; }
      out[0] = L * (1.f / 4096.f);
      out[1] = C * (100.f / 4096.f);
    }
  }
}

extern "C" void kernel_launch(void* const* d_in, const int* in_sizes, int n_in,
                              void* d_out, int out_size, void* d_ws, size_t ws_size,
                              hipStream_t stream) {
  const float* pred = (const float*)d_in[0];
  const float* gt   = (const float*)d_in[1];
  char* w = (char*)d_ws;
  unsigned short* Xbf = (unsigned short*)(w + OFF_X);
  unsigned short* Ybf = (unsigned short*)(w + OFF_Y);
  float* pmax  = (float*)(w + OFF_PMAX);
  float* psum  = (float*)(w + OFF_PSUM);
  float* diag  = (float*)(w + OFF_DIAG);
  float* lpart = (float*)(w + OFF_LPART);
  float* cpart = (float*)(w + OFF_CPART);
  int*   cnt   = (int*)(w + OFF_CNT);
  float* out   = (float*)d_out;

  transpose_stage<<<512, 256, 0, stream>>>(pred, gt, Xbf, Ybf, cnt);
  dim3 g1(32, 32);
  gemm_softmax_combine<<<g1, 256, 0, stream>>>(Xbf, Ybf, pmax, psum, diag,
                                               lpart, cpart, cnt, out);
}

// Round 2
// 94.061 us; speedup vs baseline: 1.3144x; 1.3144x over previous
//
#include <hip/hip_runtime.h>
#include <cstdint>

typedef __bf16 bf16x8 __attribute__((ext_vector_type(8)));
typedef float floatx4 __attribute__((ext_vector_type(4)));

// M = 4096 rows, C(K) = 256. GEMM block tile 256x256, K-slab 64, dbuf LDS.
//
// Staged global layout (produced by transpose_stage, consumed by GEMM):
//   Xs[rb(32)][s(4)][kk(2)][rowhi(8)][quad(4)][rowlo(16)][8 bf16]
// holding element X[row = rb*128+rowhi*16+rowlo][k = s*64+kk*32+quad*8+j].
// A 256-row block tile = two consecutive rb images; the per-slab LDS image is
// the concatenation [half(2)][kk(2)][rowhi(8)][quad(4)][rowlo(16)][8], which
// is lane-linear for global_load_lds staging AND conflict-free for
// ds_read_b128 fragment reads.

#define OFF_X     (0u)
#define OFF_Y     (2u*1024*1024)
#define OFF_PMAX  (4u*1024*1024)
#define OFF_PSUM  (5u*1024*1024)
#define OFF_DIAG  (6u*1024*1024)
#define OFF_LPART (OFF_DIAG + 16384u)
#define OFF_CPART (OFF_LPART + 256u)
#define OFF_CNT   (OFF_CPART + 256u)   // cnt[0]: combine arrival counter

#define AS1C(p) ((const __attribute__((address_space(1))) void*)(const void*)(p))
#define AS3(p)  ((__attribute__((address_space(3))) void*)(void*)(p))

// ---------------------------------------------------------------------------
// K0: pred/gt (B,N,C,H,W) fp32 -> staged bf16 layout. One block per slab
// (one (b,n) pair = 16 rows x 256 c, 16 KB contiguous input). Block 0 also
// zeroes the combine-arrival counter (visible to K2 via kernel-boundary
// release; only 1 int needed but zeroing 33 is free).
// ---------------------------------------------------------------------------
__global__ __launch_bounds__(256) void transpose_stage(
    const float* __restrict__ pred, const float* __restrict__ gt,
    unsigned short* __restrict__ Xs, unsigned short* __restrict__ Ys,
    int* __restrict__ cnt) {
  int blk = blockIdx.x;
  const int t = threadIdx.x;
  if (blk == 0 && t < 33) cnt[t] = 0;
  const float* src;
  unsigned short* dst;
  int slab;
  if (blk < 256) { src = pred; dst = Xs; slab = blk; }
  else           { src = gt;   dst = Ys; slab = blk - 256; }
  const float* sb = src + slab * 4096;
  const int rb = slab >> 3, rowhi = slab & 7;
  #pragma unroll
  for (int half = 0; half < 2; ++half) {
    int c_ = half * 256 + t;                 // chunk id within slab, 0..511
    int rowlo = c_ & 15;
    int quad  = (c_ >> 4) & 3;
    int kk    = (c_ >> 6) & 1;
    int s     = c_ >> 7;
    int k0 = s * 64 + kk * 32 + quad * 8;
    unsigned int packed[4];
    #pragma unroll
    for (int jj = 0; jj < 4; ++jj) {
      unsigned int lohi[2];
      #pragma unroll
      for (int e = 0; e < 2; ++e) {
        float f = sb[(k0 + jj * 2 + e) * 16 + rowlo];
        unsigned int u = __float_as_uint(f);
        lohi[e] = (u + 0x7FFFu + ((u >> 16) & 1u)) >> 16;   // RNE -> bf16
      }
      packed[jj] = lohi[0] | (lohi[1] << 16);
    }
    unsigned short* o = dst + rb * 32768 +
        (unsigned)(s * 1024 + kk * 512 + rowhi * 64 + quad * 16 + rowlo) * 8;
    uint4 v; v.x = packed[0]; v.y = packed[1]; v.z = packed[2]; v.w = packed[3];
    *reinterpret_cast<uint4*>(o) = v;
  }
}

// ---------------------------------------------------------------------------
// K1: lossmat tile (256x256) = X @ Y^T, mfma_f32_16x16x32_bf16.
// 512 threads, 8 waves as 2x4 (rg,cg); wave tile 128x64 = 8x4 fragments.
// K streamed in 4 slabs of 64 through double-buffered 2x(32+32) KB LDS:
// issue next slab's global_load_lds BEFORE computing current (2-phase
// pipeline, one vmcnt-drain barrier per slab). 1 block/CU; per-XCD working
// set 2.25 MB -> L2-resident. Fused per-row (max, sum-exp) partials + diag.
// NO device-scope fences here (round-1 lesson: per-block fences at 1024
// scale serialize L2 wbl2/inv and cost ~30 us).
// ---------------------------------------------------------------------------
__global__ __launch_bounds__(512) void gemm_softmax_partial(
    const unsigned short* __restrict__ Xs, const unsigned short* __restrict__ Ys,
    float* __restrict__ pmax, float* __restrict__ psum, float* __restrict__ diag) {
  __shared__ __align__(16) unsigned short As[2][16384];  // 2 x 32 KB
  __shared__ __align__(16) unsigned short Bs[2][16384];  // 2 x 32 KB
  const int t = threadIdx.x;
  const int wave = t >> 6, lane = t & 63;
  const int rg = wave >> 2, cg = wave & 3;
  const int bC = blockIdx.x, bR = blockIdx.y;
  const unsigned short* Ag = Xs + bR * 65536;   // rb groups 2bR, 2bR+1
  const unsigned short* Bg = Ys + bC * 65536;

  floatx4 acc[8][4];
  const floatx4 zero = {0.f, 0.f, 0.f, 0.f};
  #pragma unroll
  for (int i = 0; i < 8; ++i)
    #pragma unroll
    for (int j = 0; j < 4; ++j) acc[i][j] = zero;

  // Stage slab s into buffer buf: 2048 chunks x 16B per array, lane-linear.
  auto STAGE = [&](int buf, int s) {
    #pragma unroll
    for (int it = 0; it < 4; ++it) {
      int chunk = it * 512 + t;              // 0..2047
      int half = chunk >> 10, w_ = chunk & 1023;
      __builtin_amdgcn_global_load_lds(
          AS1C(Ag + half * 32768 + s * 8192 + w_ * 8),
          AS3(&As[buf][(unsigned)chunk * 8]), 16, 0, 0);
      __builtin_amdgcn_global_load_lds(
          AS1C(Bg + half * 32768 + s * 8192 + w_ * 8),
          AS3(&Bs[buf][(unsigned)chunk * 8]), 16, 0, 0);
    }
  };

  STAGE(0, 0);
  __syncthreads();                           // drain vmcnt: slab 0 resident
  int buf = 0;
  for (int s = 0; s < 4; ++s) {
    if (s < 3) STAGE(buf ^ 1, s + 1);        // in flight across compute
    #pragma unroll
    for (int kk = 0; kk < 2; ++kk) {
      bf16x8 b[4];
      #pragma unroll
      for (int fc = 0; fc < 4; ++fc) {
        int gc = cg * 4 + fc;                // 16-col group, 0..15
        b[fc] = *reinterpret_cast<const bf16x8*>(
            &Bs[buf][(unsigned)((gc >> 3) * 8192 + kk * 4096 +
                                (gc & 7) * 512 + lane * 8)]);
      }
      #pragma unroll
      for (int fr = 0; fr < 8; ++fr) {
        bf16x8 a = *reinterpret_cast<const bf16x8*>(
            &As[buf][(unsigned)(rg * 8192 + kk * 4096 + fr * 512 + lane * 8)]);
        #pragma unroll
        for (int fc = 0; fc < 4; ++fc)
          acc[fr][fc] = __builtin_amdgcn_mfma_f32_16x16x32_bf16(
              a, b[fc], acc[fr][fc], 0, 0, 0);
      }
    }
    if (s < 3) { __syncthreads(); buf ^= 1; }  // also drains next slab's loads
  }

  const int quad = lane >> 4, lc = lane & 15;

  // Diagonal: local row rg*128+fr*16+quad*4+r == local col cg*64+fc*16+lc
  // requires cg == 2*rg + (fr>>2), fc == fr&3, lc == quad*4+r.
  if (bR == bC) {
    #pragma unroll
    for (int fr = 0; fr < 8; ++fr) {
      if (cg == 2 * rg + (fr >> 2)) {
        #pragma unroll
        for (int r = 0; r < 4; ++r)
          if (lc == quad * 4 + r)
            diag[bR * 256 + rg * 128 + fr * 16 + lc] = acc[fr][fr & 3][r];
      }
    }
  }

  // Per-row partials over this wave's 64 cols (col-group bC*4+cg of 64).
  #pragma unroll
  for (int fr = 0; fr < 8; ++fr) {
    #pragma unroll
    for (int r = 0; r < 4; ++r) {
      float v0 = acc[fr][0][r], v1 = acc[fr][1][r];
      float v2 = acc[fr][2][r], v3 = acc[fr][3][r];
      float m = fmaxf(fmaxf(v0, v1), fmaxf(v2, v3));
      #pragma unroll
      for (int sh = 1; sh < 16; sh <<= 1) m = fmaxf(m, __shfl_xor(m, sh, 64));
      float ss = __expf(v0 - m) + __expf(v1 - m) +
                 __expf(v2 - m) + __expf(v3 - m);
      #pragma unroll
      for (int sh = 1; sh < 16; sh <<= 1) ss += __shfl_xor(ss, sh, 64);
      if (lc == 0) {
        int grow = bR * 256 + rg * 128 + fr * 16 + quad * 4 + r;
        int p = grow * 64 + bC * 4 + cg;
        pmax[p] = m; psum[p] = ss;
      }
    }
  }
}

// ---------------------------------------------------------------------------
// K2: per-row combine of 64 col-group partials -> loss/correct, block-reduce;
// last of the 16 blocks (device-scope arrival counter) sums the 16 partials
// and writes out. Only 16 fences total -> negligible (vs round-1's 1024).
// ---------------------------------------------------------------------------
__global__ __launch_bounds__(256) void combine_rows(
    const float* __restrict__ pmax, const float* __restrict__ psum,
    const float* __restrict__ diag,
    float* __restrict__ lpart, float* __restrict__ cpart,
    int* __restrict__ cnt, float* __restrict__ out) {
  int row = blockIdx.x * 256 + threadIdx.x;
  const float* pm = pmax + row * 64;
  const float* ps = psum + row * 64;
  float M = -3.4e38f;
  #pragma unroll 8
  for (int b = 0; b < 64; ++b) M = fmaxf(M, pm[b]);
  float S = 0.f;
  #pragma unroll 8
  for (int b = 0; b < 64; ++b) S += ps[b] * __expf(pm[b] - M);
  float d = diag[row];
  float lossr = logf(S) + M - d;
  float corr = (d == M) ? 1.f : 0.f;
  #pragma unroll
  for (int sh = 1; sh < 64; sh <<= 1) {
    lossr += __shfl_xor(lossr, sh, 64);
    corr  += __shfl_xor(corr,  sh, 64);
  }
  __shared__ float ls[4], cs[4];
  int wave = threadIdx.x >> 6, lane = threadIdx.x & 63;
  if (lane == 0) { ls[wave] = lossr; cs[wave] = corr; }
  __syncthreads();
  if (threadIdx.x == 0) {
    lpart[blockIdx.x] = ls[0] + ls[1] + ls[2] + ls[3];
    cpart[blockIdx.x] = cs[0] + cs[1] + cs[2] + cs[3];
    __threadfence();                     // release per-block partial
    if (atomicAdd(cnt, 1) == 15) {       // last arriver finalizes
      __threadfence();                   // acquire all partials
      float L = 0.f, C = 0.f;
      for (int i = 0; i < 16; ++i) { L += lpart[i]; C += cpart[i]; }
      out[0] = L * (1.f / 4096.f);
      out[1] = C * (100.f / 4096.f);
    }
  }
}

extern "C" void kernel_launch(void* const* d_in, const int* in_sizes, int n_in,
                              void* d_out, int out_size, void* d_ws, size_t ws_size,
                              hipStream_t stream) {
  const float* pred = (const float*)d_in[0];
  const float* gt   = (const float*)d_in[1];
  char* w = (char*)d_ws;
  unsigned short* Xbf = (unsigned short*)(w + OFF_X);
  unsigned short* Ybf = (unsigned short*)(w + OFF_Y);
  float* pmax  = (float*)(w + OFF_PMAX);
  float* psum  = (float*)(w + OFF_PSUM);
  float* diag  = (float*)(w + OFF_DIAG);
  float* lpart = (float*)(w + OFF_LPART);
  float* cpart = (float*)(w + OFF_CPART);
  int*   cnt   = (int*)(w + OFF_CNT);
  float* out   = (float*)d_out;

  transpose_stage<<<512, 256, 0, stream>>>(pred, gt, Xbf, Ybf, cnt);
  dim3 g1(16, 16);
  gemm_softmax_partial<<<g1, 512, 0, stream>>>(Xbf, Ybf, pmax, psum, diag);
  combine_rows<<<16, 256, 0, stream>>>(pmax, psum, diag, lpart, cpart, cnt, out);
}

// Round 3
// 92.978 us; speedup vs baseline: 1.3297x; 1.0116x over previous
//
#include <hip/hip_runtime.h>
#include <cstdint>

typedef __bf16 bf16x8 __attribute__((ext_vector_type(8)));
typedef float floatx4 __attribute__((ext_vector_type(4)));

// M = 4096 rows, C(K) = 256. Fused kernel: per-block direct staging from
// pred/gt (fp32 -> bf16 transpose in registers) into LDS, 256x256 GEMM tile,
// K-slab 64, double-buffered LDS, fused softmax partials. No global staging
// intermediate (round-0..2 lesson: the staged-global round trip + vmcnt(0)
// drain barriers left the GEMM ~8x off roofline at MfmaUtil ~5%).
//
// LDS image per slab (shorts): addr = half*8192 + kk*4096 + rowhi*512
//   + quad*128 + (rowlo ^ quad)*8 + j, holding element
//   [row = half*128 + rowhi*16 + rowlo][k = kk*32 + quad*8 + j].
// The rowlo^quad XOR spreads staging writes (which cover only rowlo===rr
// mod 4 per instruction) across banks; fragment reads stay 2-way (free).

#define OFF_PMAX  (4u*1024*1024)
#define OFF_PSUM  (5u*1024*1024)
#define OFF_DIAG  (6u*1024*1024)
#define OFF_LPART (OFF_DIAG + 16384u)
#define OFF_CPART (OFF_LPART + 256u)
#define OFF_CNT   (OFF_CPART + 256u)   // cnt[0]: combine arrival counter

__device__ __forceinline__ unsigned rne16(float f) {
  unsigned u = __float_as_uint(f);
  return (u + 0x7FFFu + ((u >> 16) & 1u)) >> 16;   // RNE -> bf16 (as round 0-2)
}

// ---------------------------------------------------------------------------
// K1: lossmat tile (256x256) = X @ Y^T, mfma_f32_16x16x32_bf16.
// 512 threads, 8 waves as 2x4 (rg,cg); wave tile 128x64 = 8x4 fragments.
// Staging: thread t = (sl<<5)|(kq8<<2)|rq owns micro-tile (4 rows x 8 k):
//   rows sl*16 + rq*4 .. +3, k = kq8*8 .. +7 of the current slab.
//   8x float4 loads (fully coalesced 64B lines), transpose via component
//   selection, RNE-pack to 4x uint4, ds_write_b128 with XOR swizzle.
// Pipeline: loads for slab s+1 issued before compute(s) (reg double-buffer
// of the *tile* is in LDS; reg set reused after WRITE consumes it).
// ---------------------------------------------------------------------------
__global__ __launch_bounds__(512) void gemm_fused(
    const float* __restrict__ pred, const float* __restrict__ gt,
    float* __restrict__ pmax, float* __restrict__ psum,
    float* __restrict__ diag, int* __restrict__ cnt) {
  __shared__ __align__(16) unsigned short As[2][16384];  // 2 x 32 KB
  __shared__ __align__(16) unsigned short Bs[2][16384];  // 2 x 32 KB
  const int t = threadIdx.x;
  const int wave = t >> 6, lane = t & 63;
  const int rg = wave >> 2, cg = wave & 3;
  const int bC = blockIdx.x, bR = blockIdx.y;
  if (bC == 0 && bR == 0 && t == 0) cnt[0] = 0;   // reset combine counter

  // Staging decomposition of t.
  const int sl = t >> 5;            // (b,n) slab within tile, 0..15
  const int kq8 = (t >> 2) & 7;     // 8-k group within slab, 0..7
  const int rq = t & 3;             // 4-row group within slab, 0..3
  const int quad_w = kq8 & 3;
  const unsigned wbase = (unsigned)(((sl >> 3) << 13) + ((kq8 >> 2) << 12) +
                                    ((sl & 7) << 9) + (quad_w << 7));
  const float* pX = pred + (((bR << 4) + sl) << 12) + (kq8 << 7) + (rq << 2);
  const float* pY = gt   + (((bC << 4) + sl) << 12) + (kq8 << 7) + (rq << 2);

  // Fragment-read lane offset with matching XOR swizzle.
  const unsigned lxor = (unsigned)(((lane >> 4) << 7) +
                                   (((lane & 15) ^ (lane >> 4)) << 3));

  floatx4 acc[8][4];
  const floatx4 zero = {0.f, 0.f, 0.f, 0.f};
  #pragma unroll
  for (int i = 0; i < 8; ++i)
    #pragma unroll
    for (int j = 0; j < 4; ++j) acc[i][j] = zero;

  float4 xa[8], ya[8];

#define LOADS(S) do {                                                        \
    _Pragma("unroll") for (int j = 0; j < 8; ++j)                            \
      xa[j] = *reinterpret_cast<const float4*>(pX + ((S) << 10) + (j << 4)); \
    _Pragma("unroll") for (int j = 0; j < 8; ++j)                            \
      ya[j] = *reinterpret_cast<const float4*>(pY + ((S) << 10) + (j << 4)); \
  } while (0)

#define STG_ROW(BUF, RR, COMP) do {                                          \
    uint4 v;                                                                 \
    unsigned off = wbase + (unsigned)((((rq << 2) + (RR)) ^ quad_w) << 3);   \
    v.x = rne16(xa[0].COMP) | (rne16(xa[1].COMP) << 16);                     \
    v.y = rne16(xa[2].COMP) | (rne16(xa[3].COMP) << 16);                     \
    v.z = rne16(xa[4].COMP) | (rne16(xa[5].COMP) << 16);                     \
    v.w = rne16(xa[6].COMP) | (rne16(xa[7].COMP) << 16);                     \
    *reinterpret_cast<uint4*>(&As[BUF][off]) = v;                            \
    v.x = rne16(ya[0].COMP) | (rne16(ya[1].COMP) << 16);                     \
    v.y = rne16(ya[2].COMP) | (rne16(ya[3].COMP) << 16);                     \
    v.z = rne16(ya[4].COMP) | (rne16(ya[5].COMP) << 16);                     \
    v.w = rne16(ya[6].COMP) | (rne16(ya[7].COMP) << 16);                     \
    *reinterpret_cast<uint4*>(&Bs[BUF][off]) = v;                            \
  } while (0)

#define WRITES(BUF) do {                                                     \
    STG_ROW(BUF, 0, x); STG_ROW(BUF, 1, y);                                  \
    STG_ROW(BUF, 2, z); STG_ROW(BUF, 3, w);                                  \
  } while (0)

#define COMPUTE(BUF) do {                                                    \
    _Pragma("unroll") for (int kk = 0; kk < 2; ++kk) {                       \
      bf16x8 b[4];                                                           \
      _Pragma("unroll") for (int fc = 0; fc < 4; ++fc) {                     \
        int gc = cg * 4 + fc;                                                \
        b[fc] = *reinterpret_cast<const bf16x8*>(                            \
            &Bs[BUF][(unsigned)((gc >> 3) * 8192 + kk * 4096 +               \
                                (gc & 7) * 512) + lxor]);                    \
      }                                                                      \
      _Pragma("unroll") for (int fr = 0; fr < 8; ++fr) {                     \
        bf16x8 a = *reinterpret_cast<const bf16x8*>(                         \
            &As[BUF][(unsigned)(rg * 8192 + kk * 4096 + fr * 512) + lxor]);  \
        _Pragma("unroll") for (int fc = 0; fc < 4; ++fc)                     \
          acc[fr][fc] = __builtin_amdgcn_mfma_f32_16x16x32_bf16(             \
              a, b[fc], acc[fr][fc], 0, 0, 0);                               \
      }                                                                      \
    }                                                                        \
  } while (0)

  LOADS(0);
  WRITES(0);
  LOADS(1);                 // slab 1 in flight during compute(0)
  __syncthreads();          // buf 0 image complete

  int buf = 0;
  COMPUTE(0);
  WRITES(1); LOADS(2); __syncthreads(); buf = 1;
  COMPUTE(1);
  WRITES(0); LOADS(3); __syncthreads(); buf = 0;
  COMPUTE(0);
  WRITES(1); __syncthreads();
  COMPUTE(1);

#undef LOADS
#undef STG_ROW
#undef WRITES
#undef COMPUTE

  const int quad = lane >> 4, lc = lane & 15;

  // Diagonal: local row rg*128+fr*16+quad*4+r == local col cg*64+fc*16+lc
  // requires cg == 2*rg + (fr>>2), fc == fr&3, lc == quad*4+r.
  if (bR == bC) {
    #pragma unroll
    for (int fr = 0; fr < 8; ++fr) {
      if (cg == 2 * rg + (fr >> 2)) {
        #pragma unroll
        for (int r = 0; r < 4; ++r)
          if (lc == quad * 4 + r)
            diag[bR * 256 + rg * 128 + fr * 16 + lc] = acc[fr][fr & 3][r];
      }
    }
  }

  // Per-row partials over this wave's 64 cols (col-group bC*4+cg of 64).
  #pragma unroll
  for (int fr = 0; fr < 8; ++fr) {
    #pragma unroll
    for (int r = 0; r < 4; ++r) {
      float v0 = acc[fr][0][r], v1 = acc[fr][1][r];
      float v2 = acc[fr][2][r], v3 = acc[fr][3][r];
      float m = fmaxf(fmaxf(v0, v1), fmaxf(v2, v3));
      #pragma unroll
      for (int sh = 1; sh < 16; sh <<= 1) m = fmaxf(m, __shfl_xor(m, sh, 64));
      float ss = __expf(v0 - m) + __expf(v1 - m) +
                 __expf(v2 - m) + __expf(v3 - m);
      #pragma unroll
      for (int sh = 1; sh < 16; sh <<= 1) ss += __shfl_xor(ss, sh, 64);
      if (lc == 0) {
        int grow = bR * 256 + rg * 128 + fr * 16 + quad * 4 + r;
        int p = grow * 64 + bC * 4 + cg;
        pmax[p] = m; psum[p] = ss;
      }
    }
  }
}

// ---------------------------------------------------------------------------
// K2: per-row combine of 64 col-group partials -> loss/correct, block-reduce;
// last of the 16 blocks (device-scope arrival counter) sums the 16 partials
// and writes out. Only 16 fences total (round-1 lesson: fences scale badly).
// ---------------------------------------------------------------------------
__global__ __launch_bounds__(256) void combine_rows(
    const float* __restrict__ pmax, const float* __restrict__ psum,
    const float* __restrict__ diag,
    float* __restrict__ lpart, float* __restrict__ cpart,
    int* __restrict__ cnt, float* __restrict__ out) {
  int row = blockIdx.x * 256 + threadIdx.x;
  const float* pm = pmax + row * 64;
  const float* ps = psum + row * 64;
  float M = -3.4e38f;
  #pragma unroll 8
  for (int b = 0; b < 64; ++b) M = fmaxf(M, pm[b]);
  float S = 0.f;
  #pragma unroll 8
  for (int b = 0; b < 64; ++b) S += ps[b] * __expf(pm[b] - M);
  float d = diag[row];
  float lossr = logf(S) + M - d;
  float corr = (d == M) ? 1.f : 0.f;
  #pragma unroll
  for (int sh = 1; sh < 64; sh <<= 1) {
    lossr += __shfl_xor(lossr, sh, 64);
    corr  += __shfl_xor(corr,  sh, 64);
  }
  __shared__ float ls[4], cs[4];
  int wave = threadIdx.x >> 6, lane = threadIdx.x & 63;
  if (lane == 0) { ls[wave] = lossr; cs[wave] = corr; }
  __syncthreads();
  if (threadIdx.x == 0) {
    lpart[blockIdx.x] = ls[0] + ls[1] + ls[2] + ls[3];
    cpart[blockIdx.x] = cs[0] + cs[1] + cs[2] + cs[3];
    __threadfence();                     // release per-block partial
    if (atomicAdd(cnt, 1) == 15) {       // last arriver finalizes
      __threadfence();                   // acquire all partials
      float L = 0.f, C = 0.f;
      for (int i = 0; i < 16; ++i) { L += lpart[i]; C += cpart[i]; }
      out[0] = L * (1.f / 4096.f);
      out[1] = C * (100.f / 4096.f);
    }
  }
}

extern "C" void kernel_launch(void* const* d_in, const int* in_sizes, int n_in,
                              void* d_out, int out_size, void* d_ws, size_t ws_size,
                              hipStream_t stream) {
  const float* pred = (const float*)d_in[0];
  const float* gt   = (const float*)d_in[1];
  char* w = (char*)d_ws;
  float* pmax  = (float*)(w + OFF_PMAX);
  float* psum  = (float*)(w + OFF_PSUM);
  float* diag  = (float*)(w + OFF_DIAG);
  float* lpart = (float*)(w + OFF_LPART);
  float* cpart = (float*)(w + OFF_CPART);
  int*   cnt   = (int*)(w + OFF_CNT);
  float* out   = (float*)d_out;

  dim3 g1(16, 16);
  gemm_fused<<<g1, 512, 0, stream>>>(pred, gt, pmax, psum, diag, cnt);
  combine_rows<<<16, 256, 0, stream>>>(pmax, psum, diag, lpart, cpart, cnt, out);
}